// Round 8
// baseline (247.112 us; speedup 1.0000x reference)
//
#include <hip/hip_runtime.h>

// LSTM: B=2048, T=512, INPUT=2, H=32, OUT=1.
// Round 12: PHASE-INTERLEAVED pair — one wave owns TWO batch elements (A,B)
// but processes them in ALTERNATING full-wave phases, not lane-packed.
//   Per phase (one element, all 64 lanes): R10's proven layout —
//   lane j=lane&31; low lanes own rows i_j,g_j; high lanes f_j,o_j;
//   permlane32_swap exchange; redundant c on both halves.
// Why: R11 measured issue ~476 cy/step (pk_fma=4cy: packing saves fetch not
// FP32 throughput; trans~8cy) + ~300 cy NAKED stall (LDS h round-trip) at the
// problem-capped 1 wave/SIMD. A and B are independent chains: ending each
// phase with {ds_write h; ds_read hq_next} lets A's LDS round-trip fly under
// B's ~250-cy phase and vice versa — latency hidden by issue, no occupancy
// needed. Weights halve vs R11 (2 rows/lane, shared by both elements).
// Math is verbatim R10/R11 (same scales, permlane orientation, chain split)
// -> absmax expected bit-identical 0.001953125.
// Carried: log2e pre-scaled weights, bare v_exp_f32 sigm, c in 2*log2e scale,
// h = fma(2*o, sigm(c'), -o), x prefetched 4 steps ahead, history rows double
// as broadcast source, per-chunk FC flush (low lanes elem A, high elem B).

#define BB 2048
#define TT 512
#define HH 32
#define CHUNK 32
#define ROWF 36                        // floats per history row (16B-aligned)
#define WS (2 * CHUNK * ROWF + 4)      // per-wave LDS floats

#define LOG2E 1.44269504088896340736f

typedef float v2f __attribute__((ext_vector_type(2)));
typedef float v4f __attribute__((ext_vector_type(4)));
typedef unsigned int v2u __attribute__((ext_vector_type(2)));

__device__ __forceinline__ float sigm2(float xs) {
    // xs is log2e-scaled: returns 1/(1+2^-xs) = sigmoid(xs/log2e)
    return __builtin_amdgcn_rcpf(1.0f + __builtin_amdgcn_exp2f(-xs));
}

__global__ __launch_bounds__(256, 1) void lstm_fused_kernel(
    const float* __restrict__ x,     // [B, T, 2]
    const float* __restrict__ W_ih,  // [128, 2]
    const float* __restrict__ W_hh,  // [128, 32]
    const float* __restrict__ b_ih,  // [128]
    const float* __restrict__ b_hh,  // [128]
    const float* __restrict__ W_fc,  // [1, 32]
    const float* __restrict__ b_fc,  // [1]
    float* __restrict__ out)         // [B, T, 1]
{
    __shared__ __align__(16) float lds_h[4][WS];    // 36.9 KB history A|B

    const int lane = threadIdx.x & 63;
    const int wv   = threadIdx.x >> 6;
    const int j    = lane & 31;
    const bool low = (lane < 32);
    const int bA   = blockIdx.x * 8 + wv * 2;
    const int bB   = bA + 1;

    // gate rows (R10 layout): low lanes -> i_j, g_j ; high lanes -> f_j, o_j
    const int rlo = j + (low ? 0 : HH);
    const int rhi = j + (low ? 2 * HH : 3 * HH);
    const float sl = LOG2E;
    const float sh = low ? 2.0f * LOG2E : LOG2E;

    const v2f wihl = ((const v2f*)W_ih)[rlo] * sl;
    const v2f wihh = ((const v2f*)W_ih)[rhi] * sh;
    const float bl = (b_ih[rlo] + b_hh[rlo]) * sl;
    const float bh = (b_ih[rhi] + b_hh[rhi]) * sh;

    v2f wlo[HH / 2], whi[HH / 2];
    #pragma unroll
    for (int k = 0; k < HH / 2; ++k) {
        wlo[k] = ((const v2f*)(W_hh + rlo * HH))[k] * sl;
        whi[k] = ((const v2f*)(W_hh + rhi * HH))[k] * sh;
    }

    // FC weights (wave-uniform)
    float wfc[HH];
    #pragma unroll
    for (int u = 0; u < HH; ++u) wfc[u] = W_fc[u];
    const float bfc = b_fc[0];

    const float Aa = low ?  4.0f * LOG2E : 1.0f;
    const float Bb = low ? -2.0f * LOG2E : 0.0f;
    const v2f binitL = {bl, 0.0f};
    const v2f binitH = {bh, 0.0f};

    float cA = 0.0f, cB = 0.0f;     // c' = 2*log2e * c_true

    float* hbA = &lds_h[wv][0];
    float* hbB = &lds_h[wv][CHUNK * ROWF];

    // h_{-1} = 0 in row CHUNK-1 (both halves write same addr+value: free)
    hbA[(CHUNK - 1) * ROWF + j] = 0.0f;
    hbB[(CHUNK - 1) * ROWF + j] = 0.0f;

    // read-ahead: issue h_{-1} broadcasts now, consume in first phases
    v4f hqA[8], hqB[8];
    {
        const v4f* ra = (const v4f*)(hbA + (CHUNK - 1) * ROWF);
        const v4f* rb = (const v4f*)(hbB + (CHUNK - 1) * ROWF);
        #pragma unroll
        for (int q = 0; q < 8; ++q) hqA[q] = ra[q];
        #pragma unroll
        for (int q = 0; q < 8; ++q) hqB[q] = rb[q];
    }

    float* wrA = hbA + j;           // row 0, col j
    float* wrB = hbB + j;

    const float* xpA = x + (size_t)bA * (TT * 2);
    const float* xpB = x + (size_t)bB * (TT * 2);
    v4f xA0 = *(const v4f*)(xpA),     xA1 = *(const v4f*)(xpA + 4);
    v4f xB0 = *(const v4f*)(xpB),     xB1 = *(const v4f*)(xpB + 4);

    // per-lane flush pointers: low lanes -> element A, high -> element B
    float* outp = (low ? (out + (size_t)bA * TT) : (out + (size_t)bB * TT)) + j;
    const float* frow = (low ? hbA : hbB) + j * ROWF;

    // one LSTM phase for one element: consumes hq, returns hnew (all lanes)
    auto step = [&](const v4f (&hq)[8], v2f xt, float& c) -> float {
        v2f aL0 = __builtin_elementwise_fma(xt, wihl, binitL);
        v2f aH0 = __builtin_elementwise_fma(xt, wihh, binitH);
        v2f aL1, aH1;
        #pragma unroll
        for (int k = 0; k < HH / 2; ++k) {
            v2f hp = (k & 1)
                ? __builtin_shufflevector(hq[k >> 1], hq[k >> 1], 2, 3)
                : __builtin_shufflevector(hq[k >> 1], hq[k >> 1], 0, 1);
            if (k < HH / 4) {
                aL0 = __builtin_elementwise_fma(hp, wlo[k], aL0);
                aH0 = __builtin_elementwise_fma(hp, whi[k], aH0);
            } else if (k == HH / 4) {
                aL1 = hp * wlo[k];
                aH1 = hp * whi[k];
            } else {
                aL1 = __builtin_elementwise_fma(hp, wlo[k], aL1);
                aH1 = __builtin_elementwise_fma(hp, whi[k], aH1);
            }
        }
        v2f aL = aL0 + aL1;
        v2f aH = aH0 + aH1;
        float glo = aL.x + aL.y;
        float ghi = aH.x + aH.y;

        float alo = sigm2(glo);                 // i (low) / f (high)
        float ahi = fmaf(Aa, sigm2(ghi), Bb);   // g' (low) / o (high)

        // permlane32_swap pair = {vdst_new, vsrc_new}:
        //   .x = (low: own, high: cross)   .y = (low: cross, high: own)
        v2u r1 = __builtin_amdgcn_permlane32_swap(
            __float_as_uint(alo), __float_as_uint(alo), false, false);
        v2u r2 = __builtin_amdgcn_permlane32_swap(
            __float_as_uint(ahi), __float_as_uint(ahi), false, false);
        float fv = __uint_as_float(r1.y);
        float iv = __uint_as_float(r1.x);
        float ov = __uint_as_float(r2.y);
        float gv = __uint_as_float(r2.x);

        c = fmaf(fv, c, iv * gv);
        float rr  = sigm2(c);
        float ov2 = ov + ov;
        return fmaf(ov2, rr, -ov);              // hnew, valid on ALL lanes
    };

    #pragma unroll 1
    for (int ch = 0; ch < TT / CHUNK; ++ch) {
        #pragma unroll 1
        for (int g = 0; g < CHUNK / 4; ++g) {
            const int t0 = ch * CHUNK + g * 4;
            // prefetch next 4-step group for both elements
            const float* nxa = (t0 + 4 < TT) ? (xpA + (t0 + 4) * 2) : xpA;
            const float* nxb = (t0 + 4 < TT) ? (xpB + (t0 + 4) * 2) : xpB;
            v4f nA0 = *(const v4f*)(nxa), nA1 = *(const v4f*)(nxa + 4);
            v4f nB0 = *(const v4f*)(nxb), nB1 = *(const v4f*)(nxb + 4);

            #pragma unroll
            for (int s = 0; s < 4; ++s) {
                v2f xtA, xtB;
                if      (s == 0) { xtA = (v2f){xA0.x, xA0.y}; xtB = (v2f){xB0.x, xB0.y}; }
                else if (s == 1) { xtA = (v2f){xA0.z, xA0.w}; xtB = (v2f){xB0.z, xB0.w}; }
                else if (s == 2) { xtA = (v2f){xA1.x, xA1.y}; xtB = (v2f){xB1.x, xB1.y}; }
                else             { xtA = (v2f){xA1.z, xA1.w}; xtB = (v2f){xB1.z, xB1.w}; }

                // ---- PHASE A: uses hqA issued one phase ago ----
                {
                    float hnew = step(hqA, xtA, cA);
                    *wrA = hnew;                         // halves dup same addr
                    const v4f* r = (const v4f*)(wrA - j); // row just written
                    #pragma unroll
                    for (int q = 0; q < 8; ++q) hqA[q] = r[q];  // read-ahead
                    wrA += ROWF;
                }
                // ---- PHASE B: A's LDS round-trip flies under this ----
                {
                    float hnew = step(hqB, xtB, cB);
                    *wrB = hnew;
                    const v4f* r = (const v4f*)(wrB - j);
                    #pragma unroll
                    for (int q = 0; q < 8; ++q) hqB[q] = r[q];
                    wrB += ROWF;
                }
            }
            xA0 = nA0; xA1 = nA1; xB0 = nB0; xB1 = nB1;
        }

        // rewind write pointers to row 0 for next chunk
        wrA -= CHUNK * ROWF;
        wrB -= CHUNK * ROWF;

        // ---- FC flush: lane j handles timestep t'=j of its element ----
        float acc = bfc;
        #pragma unroll
        for (int u = 0; u < HH; ++u)
            acc = fmaf(frow[u], wfc[u], acc);
        *outp = acc;                 // out[b][ch*CHUNK + j], coalesced runs
        outp += CHUNK;
    }
}

extern "C" void kernel_launch(void* const* d_in, const int* in_sizes, int n_in,
                              void* d_out, int out_size, void* d_ws, size_t ws_size,
                              hipStream_t stream) {
    const float* x    = (const float*)d_in[0];
    const float* W_ih = (const float*)d_in[1];
    const float* W_hh = (const float*)d_in[2];
    const float* b_ih = (const float*)d_in[3];
    const float* b_hh = (const float*)d_in[4];
    const float* W_fc = (const float*)d_in[5];
    const float* b_fc = (const float*)d_in[6];
    float* out = (float*)d_out;

    dim3 grid(BB / 8);    // 256 blocks x 4 waves x 2 elements = 2048
    dim3 block(256);
    lstm_fused_kernel<<<grid, block, 0, stream>>>(x, W_ih, W_hh, b_ih, b_hh,
                                                  W_fc, b_fc, out);
}

// Round 9
// 234.343 us; speedup vs baseline: 1.0545x; 1.0545x over previous
//
#include <hip/hip_runtime.h>

// LSTM: B=2048, T=512, INPUT=2, H=32, OUT=1.
// Round 13: 2 elements/wave, half-step STAGGER (R12) + HAND-ZIPPED issue order.
// CDNA waves issue in-order: R12's phase structure was right but left phase B's
// independent work AFTER phase A's dependent chain -> nothing filled the act
// chains or the LDS h round-trip (stall 433cy/pair). This round zips at
// statement level:
//   H1: A-acts chain interleaved with B-dot (B's 32 pk-fma cover A's ~90cy
//       act chain); ends write hA + read hqA.
//   H2: B-acts chain (short exposure), write hB + read hqB, THEN A-dot(t+1)
//       placed last so hqA has ~120-150cy cover and hqB gets A-dot + next
//       A-acts (~180cy) of cover.
// Math verbatim R12/R11/R10 (same chain split, scales, permlane orientation)
// -> absmax expected bit-identical 0.001953125.
// Carried: log2e pre-scaled weights, bare v_exp_f32 sigm, c in 2*log2e scale,
// h = fma(2*o, sigm(c'), -o), x 4-step register groups prefetched 1 group
// ahead, history rows double as broadcast source, per-chunk FC flush.

#define BB 2048
#define TT 512
#define HH 32
#define CHUNK 32
#define ROWF 36                        // floats per history row (16B-aligned)
#define WS (2 * CHUNK * ROWF + 4)      // per-wave LDS floats

#define LOG2E 1.44269504088896340736f

typedef float v2f __attribute__((ext_vector_type(2)));
typedef float v4f __attribute__((ext_vector_type(4)));
typedef unsigned int v2u __attribute__((ext_vector_type(2)));

__device__ __forceinline__ float sigm2(float xs) {
    // xs is log2e-scaled: returns 1/(1+2^-xs) = sigmoid(xs/log2e)
    return __builtin_amdgcn_rcpf(1.0f + __builtin_amdgcn_exp2f(-xs));
}

__device__ __forceinline__ v2f hpick(const v4f (&hq)[8], int k) {
    return (k & 1)
        ? __builtin_shufflevector(hq[k >> 1], hq[k >> 1], 2, 3)
        : __builtin_shufflevector(hq[k >> 1], hq[k >> 1], 0, 1);
}

__global__ __launch_bounds__(256, 1) void lstm_fused_kernel(
    const float* __restrict__ x,     // [B, T, 2]
    const float* __restrict__ W_ih,  // [128, 2]
    const float* __restrict__ W_hh,  // [128, 32]
    const float* __restrict__ b_ih,  // [128]
    const float* __restrict__ b_hh,  // [128]
    const float* __restrict__ W_fc,  // [1, 32]
    const float* __restrict__ b_fc,  // [1]
    float* __restrict__ out)         // [B, T, 1]
{
    __shared__ __align__(16) float lds_h[4][WS];    // 36.9 KB history A|B

    const int lane = threadIdx.x & 63;
    const int wv   = threadIdx.x >> 6;
    const int j    = lane & 31;
    const bool low = (lane < 32);
    const int bA   = blockIdx.x * 8 + wv * 2;
    const int bB   = bA + 1;

    // gate rows (R10 layout): low lanes -> i_j, g_j ; high lanes -> f_j, o_j
    const int rlo = j + (low ? 0 : HH);
    const int rhi = j + (low ? 2 * HH : 3 * HH);
    const float sl = LOG2E;
    const float sh = low ? 2.0f * LOG2E : LOG2E;

    const v2f wihl = ((const v2f*)W_ih)[rlo] * sl;
    const v2f wihh = ((const v2f*)W_ih)[rhi] * sh;
    const float bl = (b_ih[rlo] + b_hh[rlo]) * sl;
    const float bh = (b_ih[rhi] + b_hh[rhi]) * sh;

    v2f wlo[HH / 2], whi[HH / 2];
    #pragma unroll
    for (int k = 0; k < HH / 2; ++k) {
        wlo[k] = ((const v2f*)(W_hh + rlo * HH))[k] * sl;
        whi[k] = ((const v2f*)(W_hh + rhi * HH))[k] * sh;
    }

    // FC weights (wave-uniform)
    float wfc[HH];
    #pragma unroll
    for (int u = 0; u < HH; ++u) wfc[u] = W_fc[u];
    const float bfc = b_fc[0];

    const float Aa = low ?  4.0f * LOG2E : 1.0f;
    const float Bb = low ? -2.0f * LOG2E : 0.0f;
    const v2f binitL = {bl, 0.0f};
    const v2f binitH = {bh, 0.0f};

    float cA = 0.0f, cB = 0.0f;     // c' = 2*log2e * c_true

    float* hbA = &lds_h[wv][0];
    float* hbB = &lds_h[wv][CHUNK * ROWF];

    // h_{-1} = 0 in row CHUNK-1 (both halves write same addr+value: free)
    hbA[(CHUNK - 1) * ROWF + j] = 0.0f;
    hbB[(CHUNK - 1) * ROWF + j] = 0.0f;

    v4f hqA[8], hqB[8];
    {
        const v4f* ra = (const v4f*)(hbA + (CHUNK - 1) * ROWF);
        const v4f* rb = (const v4f*)(hbB + (CHUNK - 1) * ROWF);
        #pragma unroll
        for (int q = 0; q < 8; ++q) hqA[q] = ra[q];
        #pragma unroll
        for (int q = 0; q < 8; ++q) hqB[q] = rb[q];
    }

    float* wrA = hbA + j;           // row 0, col j
    float* wrB = hbB + j;

    const float* xpA = x + (size_t)bA * (TT * 2);
    const float* xpB = x + (size_t)bB * (TT * 2);
    // current 4-step group x registers
    v4f xA0 = *(const v4f*)(xpA),  xA1 = *(const v4f*)(xpA + 4);
    v4f xB0 = *(const v4f*)(xpB),  xB1 = *(const v4f*)(xpB + 4);

    // per-lane flush pointers: low lanes -> element A, high -> element B
    float* outp = (low ? (out + (size_t)bA * TT) : (out + (size_t)bB * TT)) + j;
    const float* frow = (low ? hbA : hbB) + j * ROWF;

    // ---- software-pipeline prologue: A-dot(0) -> gloA, ghiA ----
    float gloA, ghiA;
    {
        v2f xt = (v2f){xA0.x, xA0.y};
        v2f aL0 = __builtin_elementwise_fma(xt, wihl, binitL);
        v2f aH0 = __builtin_elementwise_fma(xt, wihh, binitH);
        v2f aL1, aH1;
        #pragma unroll
        for (int k = 0; k < HH / 2; ++k) {
            v2f hp = hpick(hqA, k);
            if (k < HH / 4) {
                aL0 = __builtin_elementwise_fma(hp, wlo[k], aL0);
                aH0 = __builtin_elementwise_fma(hp, whi[k], aH0);
            } else if (k == HH / 4) {
                aL1 = hp * wlo[k];
                aH1 = hp * whi[k];
            } else {
                aL1 = __builtin_elementwise_fma(hp, wlo[k], aL1);
                aH1 = __builtin_elementwise_fma(hp, whi[k], aH1);
            }
        }
        v2f aL = aL0 + aL1, aH = aH0 + aH1;
        gloA = aL.x + aL.y;
        ghiA = aH.x + aH.y;
    }

    #pragma unroll 1
    for (int ch = 0; ch < TT / CHUNK; ++ch) {
        #pragma unroll 1
        for (int g = 0; g < CHUNK / 4; ++g) {
            const int t0 = ch * CHUNK + g * 4;
            // prefetch NEXT group's x (dummy reload at the very end)
            const float* nxa = (t0 + 4 < TT) ? (xpA + (t0 + 4) * 2) : xpA;
            const float* nxb = (t0 + 4 < TT) ? (xpB + (t0 + 4) * 2) : xpB;
            v4f nA0 = *(const v4f*)(nxa), nA1 = *(const v4f*)(nxa + 4);
            v4f nB0 = *(const v4f*)(nxb), nB1 = *(const v4f*)(nxb + 4);

            #pragma unroll
            for (int s = 0; s < 4; ++s) {
                // x for B's current step and A's NEXT step
                v2f xtB, xtAn;
                if      (s == 0) xtB = (v2f){xB0.x, xB0.y};
                else if (s == 1) xtB = (v2f){xB0.z, xB0.w};
                else if (s == 2) xtB = (v2f){xB1.x, xB1.y};
                else             xtB = (v2f){xB1.z, xB1.w};
                if      (s == 0) xtAn = (v2f){xA0.z, xA0.w};
                else if (s == 1) xtAn = (v2f){xA1.x, xA1.y};
                else if (s == 2) xtAn = (v2f){xA1.z, xA1.w};
                else             xtAn = (v2f){nA0.x, nA0.y};

                // ================= H1 =================
                // A-acts chain interleaved with B-dot (independent filler)
                float aloA = sigm2(gloA);
                float shiA = sigm2(ghiA);

                // B-dot part 1: x-proj + k=0..7 (fills A's sigm latency)
                v2f bL0 = __builtin_elementwise_fma(xtB, wihl, binitL);
                v2f bH0 = __builtin_elementwise_fma(xtB, wihh, binitH);
                #pragma unroll
                for (int k = 0; k < HH / 4; ++k) {
                    v2f hp = hpick(hqB, k);
                    bL0 = __builtin_elementwise_fma(hp, wlo[k], bL0);
                    bH0 = __builtin_elementwise_fma(hp, whi[k], bH0);
                }

                float ahiA = fmaf(Aa, shiA, Bb);
                v2u r1A = __builtin_amdgcn_permlane32_swap(
                    __float_as_uint(aloA), __float_as_uint(aloA), false, false);
                v2u r2A = __builtin_amdgcn_permlane32_swap(
                    __float_as_uint(ahiA), __float_as_uint(ahiA), false, false);
                float fvA = __uint_as_float(r1A.y);
                float ivA = __uint_as_float(r1A.x);
                float ovA = __uint_as_float(r2A.y);
                float gvA = __uint_as_float(r2A.x);
                cA = fmaf(fvA, cA, ivA * gvA);

                // B-dot part 2: k=8..15 (fills cA's sigm latency)
                v2f bL1, bH1;
                #pragma unroll
                for (int k = HH / 4; k < HH / 2; ++k) {
                    v2f hp = hpick(hqB, k);
                    if (k == HH / 4) { bL1 = hp * wlo[k]; bH1 = hp * whi[k]; }
                    else {
                        bL1 = __builtin_elementwise_fma(hp, wlo[k], bL1);
                        bH1 = __builtin_elementwise_fma(hp, whi[k], bH1);
                    }
                }

                float rrA = sigm2(cA);
                float hnA = fmaf(ovA + ovA, rrA, -ovA);

                // write hA_t, immediately issue next hqA broadcast
                *wrA = hnA;
                {
                    const v4f* r = (const v4f*)(wrA - j);
                    #pragma unroll
                    for (int q = 0; q < 8; ++q) hqA[q] = r[q];
                }
                wrA += ROWF;

                // B reduce (after the read issue: adds cover distance)
                v2f bL = bL0 + bL1, bH = bH0 + bH1;
                float gloB = bL.x + bL.y;
                float ghiB = bH.x + bH.y;

                // ================= H2 =================
                // B-acts chain (short), then write/read B, then A-dot(t+1)
                float aloB = sigm2(gloB);
                float shiB = sigm2(ghiB);
                float ahiB = fmaf(Aa, shiB, Bb);
                v2u r1B = __builtin_amdgcn_permlane32_swap(
                    __float_as_uint(aloB), __float_as_uint(aloB), false, false);
                v2u r2B = __builtin_amdgcn_permlane32_swap(
                    __float_as_uint(ahiB), __float_as_uint(ahiB), false, false);
                float fvB = __uint_as_float(r1B.y);
                float ivB = __uint_as_float(r1B.x);
                float ovB = __uint_as_float(r2B.y);
                float gvB = __uint_as_float(r2B.x);
                cB = fmaf(fvB, cB, ivB * gvB);
                float rrB = sigm2(cB);
                float hnB = fmaf(ovB + ovB, rrB, -ovB);

                *wrB = hnB;
                {
                    const v4f* r = (const v4f*)(wrB - j);
                    #pragma unroll
                    for (int q = 0; q < 8; ++q) hqB[q] = r[q];
                }
                wrB += ROWF;

                // A-dot(t+1): consumes hqA read in H1 (~full B-chain of cover)
                {
                    v2f aL0 = __builtin_elementwise_fma(xtAn, wihl, binitL);
                    v2f aH0 = __builtin_elementwise_fma(xtAn, wihh, binitH);
                    v2f aL1, aH1;
                    #pragma unroll
                    for (int k = 0; k < HH / 2; ++k) {
                        v2f hp = hpick(hqA, k);
                        if (k < HH / 4) {
                            aL0 = __builtin_elementwise_fma(hp, wlo[k], aL0);
                            aH0 = __builtin_elementwise_fma(hp, whi[k], aH0);
                        } else if (k == HH / 4) {
                            aL1 = hp * wlo[k];
                            aH1 = hp * whi[k];
                        } else {
                            aL1 = __builtin_elementwise_fma(hp, wlo[k], aL1);
                            aH1 = __builtin_elementwise_fma(hp, whi[k], aH1);
                        }
                    }
                    v2f aL = aL0 + aL1, aH = aH0 + aH1;
                    gloA = aL.x + aL.y;
                    ghiA = aH.x + aH.y;
                }
            }
            xA0 = nA0; xA1 = nA1; xB0 = nB0; xB1 = nB1;
        }

        // rewind write pointers to row 0 for next chunk
        wrA -= CHUNK * ROWF;
        wrB -= CHUNK * ROWF;

        // ---- FC flush: lane j handles timestep t'=j of its element ----
        float acc = bfc;
        #pragma unroll
        for (int u = 0; u < HH; ++u)
            acc = fmaf(frow[u], wfc[u], acc);
        *outp = acc;                 // out[b][ch*CHUNK + j]
        outp += CHUNK;
    }
}

extern "C" void kernel_launch(void* const* d_in, const int* in_sizes, int n_in,
                              void* d_out, int out_size, void* d_ws, size_t ws_size,
                              hipStream_t stream) {
    const float* x    = (const float*)d_in[0];
    const float* W_ih = (const float*)d_in[1];
    const float* W_hh = (const float*)d_in[2];
    const float* b_ih = (const float*)d_in[3];
    const float* b_hh = (const float*)d_in[4];
    const float* W_fc = (const float*)d_in[5];
    const float* b_fc = (const float*)d_in[6];
    float* out = (float*)d_out;

    dim3 grid(BB / 8);    // 256 blocks x 4 waves x 2 elements = 2048
    dim3 block(256);
    lstm_fused_kernel<<<grid, block, 0, stream>>>(x, W_ih, W_hh, b_ih, b_hh,
                                                  W_fc, b_fc, out);
}

// Round 10
// 194.090 us; speedup vs baseline: 1.2732x; 1.2074x over previous
//
#include <hip/hip_runtime.h>

// LSTM: B=2048, T=512, INPUT=2, H=32, OUT=1.
// Round 14 = Round 11 (lane-packed 2 elem/wave, the session best: 166.5us)
// with the recurrent dot moved to v_dot2_f32_f16 (f16 MACs, FP32 accumulate):
//  - R11 counter decomposition: busy 490 cy/pair-step, of which 256 cy is
//    64x v_pk_fma_f32 -- the FP32 VALU MAC floor. fdot2 does 2 f16 MACs/lane
//    at DL rate with fp32 accum -> MAC issue ~halves.
//  - h history stored as f16 in LDS: broadcast = 4x ds_read_b128 (was 8).
//  - W_hh / W_fc pre-packed to f16 pairs in registers (scaled by log2e).
//  - x-projection, biases, activations, c-recurrence all remain fp32.
// Precision: f16 quantization of h/W_hh adds ~2-5e-3 output drift on top of
// 1.95e-3; threshold is 9.34e-3. If absmax fails -> revert to R11.
// Structure carried verbatim from R11: lanes 0..31 elem A, 32..63 elem B;
// lane owns rows i_j, f_j, g_j, o_j of unit j=lane&31 (all activations
// lane-local, no exchange); history rows double as broadcast source
// (rd = wr - j); log2e folded into weights; c in 2*log2e scale;
// h = fma(2*o, sigm(c'), -o); bare v_exp_f32; x prefetched 4 steps ahead;
// per-chunk FC flush (lane j handles timestep j).

#define BB 2048
#define TT 512
#define HH 32
#define CHUNK 32
#define ROWH 40                         // f16 per history row (80 B, 16B-aligned)
#define WSH (2 * CHUNK * ROWH + 8)      // per-wave LDS f16 count

#define LOG2E 1.44269504088896340736f

typedef float v2f __attribute__((ext_vector_type(2)));
typedef float v4f __attribute__((ext_vector_type(4)));
typedef unsigned int v4u __attribute__((ext_vector_type(4)));
typedef _Float16 h2 __attribute__((ext_vector_type(2)));

__device__ __forceinline__ float sigm2(float xs) {
    // xs is log2e-scaled: returns 1/(1+2^-xs) = sigmoid(xs/log2e)
    return __builtin_amdgcn_rcpf(1.0f + __builtin_amdgcn_exp2f(-xs));
}

__device__ __forceinline__ h2 u2h(unsigned int u) {
    return __builtin_bit_cast(h2, u);
}

#if defined(__has_builtin)
#if __has_builtin(__builtin_amdgcn_fdot2)
#define FDOT2(a, b, c) __builtin_amdgcn_fdot2((a), (b), (c), false)
#endif
#endif
#ifndef FDOT2
#define FDOT2(a, b, c) fmaf((float)(a).y, (float)(b).y, \
                            fmaf((float)(a).x, (float)(b).x, (c)))
#endif

__global__ __launch_bounds__(256, 1) void lstm_fused_kernel(
    const float* __restrict__ x,     // [B, T, 2]
    const float* __restrict__ W_ih,  // [128, 2]
    const float* __restrict__ W_hh,  // [128, 32]
    const float* __restrict__ b_ih,  // [128]
    const float* __restrict__ b_hh,  // [128]
    const float* __restrict__ W_fc,  // [1, 32]
    const float* __restrict__ b_fc,  // [1]
    float* __restrict__ out)         // [B, T, 1]
{
    __shared__ __align__(16) _Float16 lds_h[4][WSH];   // ~20.5 KB history A|B

    const int lane = threadIdx.x & 63;
    const int wv   = threadIdx.x >> 6;
    const int j    = lane & 31;
    const bool low = (lane < 32);
    const int b    = blockIdx.x * 8 + wv * 2 + (low ? 0 : 1);

    // gate rows for unit j (PyTorch order: i, f, g, o)
    const int ri = j, rf = HH + j, rg = 2 * HH + j, ro = 3 * HH + j;
    const float si = LOG2E;              // i, f, o scale
    const float sg = 2.0f * LOG2E;       // g scale (tanh doubling folded in)

    // x-projection weights/biases stay fp32
    const v2f wihI = ((const v2f*)W_ih)[ri] * si;
    const v2f wihF = ((const v2f*)W_ih)[rf] * si;
    const v2f wihG = ((const v2f*)W_ih)[rg] * sg;
    const v2f wihO = ((const v2f*)W_ih)[ro] * si;
    const float bI = (b_ih[ri] + b_hh[ri]) * si;
    const float bF = (b_ih[rf] + b_hh[rf]) * si;
    const float bG = (b_ih[rg] + b_hh[rg]) * sg;
    const float bO = (b_ih[ro] + b_hh[ro]) * si;

    // recurrent weights: scaled fp32 -> packed f16 pairs (64 VGPRs)
    h2 wI[16], wF[16], wG[16], wO[16];
    #pragma unroll
    for (int k = 0; k < 16; ++k) {
        v2f a;
        a = ((const v2f*)(W_hh + ri * HH))[k] * si;
        wI[k] = (h2){(_Float16)a.x, (_Float16)a.y};
        a = ((const v2f*)(W_hh + rf * HH))[k] * si;
        wF[k] = (h2){(_Float16)a.x, (_Float16)a.y};
        a = ((const v2f*)(W_hh + rg * HH))[k] * sg;
        wG[k] = (h2){(_Float16)a.x, (_Float16)a.y};
        a = ((const v2f*)(W_hh + ro * HH))[k] * si;
        wO[k] = (h2){(_Float16)a.x, (_Float16)a.y};
    }

    // FC weights packed f16
    h2 wfc2[16];
    #pragma unroll
    for (int k = 0; k < 16; ++k) {
        v2f a = ((const v2f*)W_fc)[k];
        wfc2[k] = (h2){(_Float16)a.x, (_Float16)a.y};
    }
    const float bfc = b_fc[0];

    float c = 0.0f;   // c' = 2*log2e * c_true

    _Float16* hb = &lds_h[wv][low ? 0 : CHUNK * ROWH];
    _Float16* wr = hb + j;                        // row 0, col j

    hb[(CHUNK - 1) * ROWH + j] = (_Float16)0.0f;  // h_{-1} row = 0

    // h broadcast registers: 32 f16 = 4 x b128 (uniform addr per half-wave)
    v4u hq[4];
    {
        const v4u* rq = (const v4u*)(hb + (CHUNK - 1) * ROWH);
        #pragma unroll
        for (int q = 0; q < 4; ++q) hq[q] = rq[q];
    }

    const float* xb = x + (size_t)b * (TT * 2);
    float* outp = out + (size_t)b * TT + j;

    // x prefetch: 4 timesteps = 2 x b128 (2 unique addrs/wave)
    v4f xq0 = *(const v4f*)(xb);
    v4f xq1 = *(const v4f*)(xb + 4);

    #pragma unroll 1
    for (int ch = 0; ch < TT / CHUNK; ++ch) {
        #pragma unroll 1
        for (int uu = 0; uu < CHUNK; uu += 4) {
            const int t = ch * CHUNK + uu;
            const float* xnx = (t + 4 < TT) ? (xb + (t + 4) * 2) : xb;
            v4f nxq0 = *(const v4f*)(xnx);
            v4f nxq1 = *(const v4f*)(xnx + 4);

            #pragma unroll
            for (int s = 0; s < 4; ++s) {
                v2f xt;
                if      (s == 0) xt = (v2f){xq0.x, xq0.y};
                else if (s == 1) xt = (v2f){xq0.z, xq0.w};
                else if (s == 2) xt = (v2f){xq1.x, xq1.y};
                else             xt = (v2f){xq1.z, xq1.w};

                // x-projection + bias in fp32 (seeds chain 0 of each gate)
                float aI0 = fmaf(xt.y, wihI.y, fmaf(xt.x, wihI.x, bI));
                float aF0 = fmaf(xt.y, wihF.y, fmaf(xt.x, wihF.x, bF));
                float aG0 = fmaf(xt.y, wihG.y, fmaf(xt.x, wihG.x, bG));
                float aO0 = fmaf(xt.y, wihO.y, fmaf(xt.x, wihO.x, bO));
                float aI1, aF1, aG1, aO1;

                // recurrent dot: 4 gates x 16 fdot2 (f16 MACs, fp32 accum),
                // split into 2 chains of 8 per gate
                #pragma unroll
                for (int k = 0; k < 16; ++k) {
                    h2 hp = u2h(hq[k >> 2][k & 3]);
                    if (k < 8) {
                        aI0 = FDOT2(hp, wI[k], aI0);
                        aF0 = FDOT2(hp, wF[k], aF0);
                        aG0 = FDOT2(hp, wG[k], aG0);
                        aO0 = FDOT2(hp, wO[k], aO0);
                    } else if (k == 8) {
                        aI1 = FDOT2(hp, wI[k], 0.0f);
                        aF1 = FDOT2(hp, wF[k], 0.0f);
                        aG1 = FDOT2(hp, wG[k], 0.0f);
                        aO1 = FDOT2(hp, wO[k], 0.0f);
                    } else {
                        aI1 = FDOT2(hp, wI[k], aI1);
                        aF1 = FDOT2(hp, wF[k], aF1);
                        aG1 = FDOT2(hp, wG[k], aG1);
                        aO1 = FDOT2(hp, wO[k], aO1);
                    }
                }
                float gi = aI0 + aI1;
                float gf = aF0 + aF1;
                float gg = aG0 + aG1;
                float go = aO0 + aO1;

                // activations: all lane-local (fp32)
                float iv = sigm2(gi);
                float fv = sigm2(gf);
                float ov = sigm2(go);
                float gv = fmaf(4.0f * LOG2E, sigm2(gg), -2.0f * LOG2E);

                // c' = f*c' + i*g'   (2*log2e scale)
                c = fmaf(fv, c, iv * gv);

                // h = o*tanh(c) = fma(2*o, sigm(c'), -o)
                float rr   = sigm2(c);
                float hnew = fmaf(ov + ov, rr, -ov);

                // write h_t (f16) into history row; that row IS next step's
                // broadcast source
                *wr = (_Float16)hnew;
                {
                    const v4u* rq = (const v4u*)(wr - j);
                    #pragma unroll
                    for (int q = 0; q < 4; ++q) hq[q] = rq[q];
                }
                wr += ROWH;
            }
            xq0 = nxq0; xq1 = nxq1;
        }

        // rewind write ptr; hq carries h across the chunk boundary
        wr -= CHUNK * ROWH;

        // ---- FC flush: lane j handles timestep t'=j of its element ----
        {
            const v4u* fr = (const v4u*)(hb + j * ROWH);
            v4u f[4];
            #pragma unroll
            for (int q = 0; q < 4; ++q) f[q] = fr[q];
            float acc = bfc;
            #pragma unroll
            for (int k = 0; k < 16; ++k)
                acc = FDOT2(u2h(f[k >> 2][k & 3]), wfc2[k], acc);
            *outp = acc;           // out[b][ch*CHUNK + j]
            outp += CHUNK;
        }
    }
}

extern "C" void kernel_launch(void* const* d_in, const int* in_sizes, int n_in,
                              void* d_out, int out_size, void* d_ws, size_t ws_size,
                              hipStream_t stream) {
    const float* x    = (const float*)d_in[0];
    const float* W_ih = (const float*)d_in[1];
    const float* W_hh = (const float*)d_in[2];
    const float* b_ih = (const float*)d_in[3];
    const float* b_hh = (const float*)d_in[4];
    const float* W_fc = (const float*)d_in[5];
    const float* b_fc = (const float*)d_in[6];
    float* out = (float*)d_out;

    dim3 grid(BB / 8);    // 256 blocks x 4 waves x 2 elements = 2048
    dim3 block(256);
    lstm_fused_kernel<<<grid, block, 0, stream>>>(x, W_ih, W_hh, b_ih, b_hh,
                                                  W_fc, b_fc, out);
}